// Round 5
// baseline (17715.048 us; speedup 1.0000x reference)
//
#include <hip/hip_runtime.h>
#include <cstdint>
#include <cstddef>

typedef unsigned short u16;
typedef unsigned int u32;
typedef __attribute__((ext_vector_type(8))) short short8;
typedef __attribute__((ext_vector_type(4))) float f32x4;

#define AGENT_SCOPE __HIP_MEMORY_SCOPE_AGENT
#define SPIN_CAP 20000000
#define POLL_CAP 200000
#define SENT 0xFFFFFFFFu

__device__ __forceinline__ u16 f2bf(float f) {
  u32 u = __float_as_uint(f);
  return (u16)((u + 0x7FFFu + ((u >> 16) & 1u)) >> 16);
}
__device__ __forceinline__ float bf2f(u16 s) { return __uint_as_float(((u32)s) << 16); }
__device__ __forceinline__ float sigm(float x) { return 1.f / (1.f + __expf(-x)); }
__device__ __forceinline__ float tanha(float x) { return 1.f - 2.f / (__expf(2.f * x) + 1.f); }
__device__ __forceinline__ void wait_vm0() { asm volatile("s_waitcnt vmcnt(0)" ::: "memory"); }

// Barrier-free persistent LSTM autoencoder, two-phase handoff.
// col = bid&3 (16 batches), rowg = bid>>2 in [0,64) (8 hidden units).
// Producers: SENT-ringed data stores (depth-3) + an UNORDERED per-WG seq flag.
// Consumers: spin on the 4-line flag region (cheap), then one SENT-verified
// 32KB data fetch (the SENT check covers the flag/data race). Cuts the LLC
// poll traffic ~30x vs polling the data lines themselves (R4).
__global__ void __launch_bounds__(256, 1)
lstm_ae_kernel(const float* __restrict__ x,
    const float* __restrict__ eWih0, const float* __restrict__ eWhh0,
    const float* __restrict__ ebi0,  const float* __restrict__ ebh0,
    const float* __restrict__ eWih1, const float* __restrict__ eWhh1,
    const float* __restrict__ ebi1,  const float* __restrict__ ebh1,
    const float* __restrict__ dWhh0,
    const float* __restrict__ dbi0,  const float* __restrict__ dbh0,
    const float* __restrict__ dWih1, const float* __restrict__ dWhh1,
    const float* __restrict__ dbi1,  const float* __restrict__ dbh1,
    const float* __restrict__ tlW,   const float* __restrict__ tlb,
    const float* __restrict__ lhW,   const float* __restrict__ lhb,
    const float* __restrict__ opW,   const float* __restrict__ opb,
    float* __restrict__ out, char* __restrict__ wsb)
{
  __shared__ __align__(16) u16 sH0[16 * 520];
  __shared__ __align__(16) u16 sH1[16 * 520];
  __shared__ __align__(16) u16 sX[16 * 136];
  __shared__ float sP[8 * 256];   // 0,1: L0 n0/n1 | 2,3: L1 main | 4,5: L1 partial | 6,7: recon partial
  __shared__ float sBias[64];
  __shared__ float sC[256];
  __shared__ float sZ[16 * 64];
  __shared__ float sOPB[2];

  u32* gcnt  = (u32*)wsb;
  float* zbuf= (float*)(wsb + 4096);
  u32* flags = (u32*)(wsb + 24576);              // [4 col][64 rowg] dwords
  u32* h0r   = (u32*)(wsb + 32768);              // [3 q][4 col][64 rowg][64 dw]
  u32* h1r   = (u32*)(wsb + 229376);

  const int tid  = threadIdx.x;
  const int col  = blockIdx.x & 3;
  const int rowg = blockIdx.x >> 2;
  const int wid  = tid >> 6;
  const int lane = tid & 63;
  const int m    = lane & 15;
  const int qo   = (lane >> 4) * 8;

  u32* myflag = &flags[col * 64 + rowg];

  // phase A: cheap spin on the column's 64 packed flags (4 lines)
  auto flag_wait = [&](u32 target) {
    const u32* fp = &flags[col * 64 + lane];
    int it = 0;
    while (it++ < POLL_CAP) {
      u32 v = __hip_atomic_load(fp, __ATOMIC_RELAXED, AGENT_SCOPE);
      if (__ballot(v >= target) == ~0ull) break;
    }
  };

  // phase B: SENT-verified data fetch + LDS scatter (usually 1 iteration)
  auto stage_slot = [&](int q0, int q1, bool p0on, bool p1on) {
    const u32* b0 = h0r + ((q0 * 4 + col) << 12) + tid;
    const u32* b1 = h1r + ((q1 * 4 + col) << 12) + tid;
    u32 v0[16], v1[16];
    int it = 0; bool ok = false;
    while (!ok && it++ < POLL_CAP) {
      ok = true;
      if (p0on) {
        #pragma unroll
        for (int i = 0; i < 16; ++i) {
          v0[i] = __hip_atomic_load(b0 + i * 256, __ATOMIC_RELAXED, AGENT_SCOPE);
          ok &= (v0[i] != SENT);
        }
      }
      if (p1on) {
        #pragma unroll
        for (int i = 0; i < 16; ++i) {
          v1[i] = __hip_atomic_load(b1 + i * 256, __ATOMIC_RELAXED, AGENT_SCOPE);
          ok &= (v1[i] != SENT);
        }
      }
    }
    u32* dH0 = (u32*)sH0; u32* dH1 = (u32*)sH1;
    #pragma unroll
    for (int i = 0; i < 16; ++i) {
      int g = i * 256 + tid;
      int rg = g >> 6, b = (g >> 2) & 15, udw = g & 3;
      if (p0on) dH0[b * 260 + rg * 4 + udw] = v0[i];
      if (p1on) dH1[b * 260 + rg * 4 + udw] = v1[i];
    }
  };

  auto clears = [&](int s) {
    if (tid < 64) {
      int cq0 = (s + 1) % 3, cq1 = s % 3;
      __hip_atomic_store(h0r + ((cq0 * 4 + col) << 12) + (rowg << 6) + tid,
                         SENT, __ATOMIC_RELAXED, AGENT_SCOPE);
      __hip_atomic_store(h1r + ((cq1 * 4 + col) << 12) + (rowg << 6) + tid,
                         SENT, __ATOMIC_RELAXED, AGENT_SCOPE);
    }
  };

  auto stage_xt = [&](int s) {
    int b = tid >> 4, seg = tid & 15;
    const float* p = x + (size_t)(col * 16 + b) * 131072 + (size_t)s * 128 + seg * 8;
    float4 f0 = *(const float4*)p, f1 = *(const float4*)(p + 4);
    uint4 v;
    v.x = (u32)f2bf(f0.x) | ((u32)f2bf(f0.y) << 16);
    v.y = (u32)f2bf(f0.z) | ((u32)f2bf(f0.w) << 16);
    v.z = (u32)f2bf(f1.x) | ((u32)f2bf(f1.y) << 16);
    v.w = (u32)f2bf(f1.z) | ((u32)f2bf(f1.w) << 16);
    *(uint4*)(sX + b * 136 + seg * 8) = v;
  };

  auto ldw = [&](const float* W, int ld, int row, int kofs) -> short8 {
    const float* p = W + (size_t)row * ld + kofs + qo;
    float4 f0 = *(const float4*)p, f1 = *(const float4*)(p + 4);
    short8 r;
    r[0] = (short)f2bf(f0.x); r[1] = (short)f2bf(f0.y);
    r[2] = (short)f2bf(f0.z); r[3] = (short)f2bf(f0.w);
    r[4] = (short)f2bf(f1.x); r[5] = (short)f2bf(f1.y);
    r[6] = (short)f2bf(f1.z); r[7] = (short)f2bf(f1.w);
    return r;
  };

  auto spstore = [&](int slot, const f32x4& a) {
    int mb = (lane >> 4) * 4;
    #pragma unroll
    for (int r = 0; r < 4; ++r) sP[slot * 256 + (mb + r) * 16 + m] = a[r];
  };

  // gates: L0 = slots 0,1 (full); L1 = slots 2,3 (main) + 4,5 (partials)
  auto act_store = [&](bool L0a, bool L1a, int q0, int q1) {
    int li = tid >> 7, b = (tid >> 3) & 15, u = tid & 7;
    bool actv = li ? L1a : L0a;
    float hv = 0.f;
    if (actv) {
      float gi, gf, gg, go;
      if (li == 0) {
        gi = sP[0*256 + b*16 + u];       gf = sP[0*256 + b*16 + 8 + u];
        gg = sP[1*256 + b*16 + u];       go = sP[1*256 + b*16 + 8 + u];
      } else {
        gi = sP[2*256 + b*16 + u]     + sP[4*256 + b*16 + u];
        gf = sP[2*256 + b*16 + 8 + u] + sP[4*256 + b*16 + 8 + u];
        gg = sP[3*256 + b*16 + u]     + sP[5*256 + b*16 + u];
        go = sP[3*256 + b*16 + 8 + u] + sP[5*256 + b*16 + 8 + u];
      }
      gi += sBias[li*32 + u];      gf += sBias[li*32 + 8 + u];
      gg += sBias[li*32 + 16 + u]; go += sBias[li*32 + 24 + u];
      float c = sC[(li*16 + b)*8 + u];
      c = sigm(gf)*c + sigm(gi)*tanha(gg);
      sC[(li*16 + b)*8 + u] = c;
      hv = sigm(go)*tanha(c);
    }
    u16 hb = f2bf(hv);
    u32 other = __shfl_xor((u32)hb, 1);
    if (actv && !(u & 1)) {
      u32 v = (u32)hb | (other << 16);
      u32* ring = li ? h1r : h0r;
      int q = li ? q1 : q0;
      __hip_atomic_store(ring + ((q * 4 + col) << 12) + (rowg << 6) + b * 4 + (u >> 1),
                         v, __ATOMIC_RELAXED, AGENT_SCOPE);
    }
  };

  auto gbar = [&](u32 target) {
    __syncthreads();
    if (tid == 0) {
      __hip_atomic_fetch_add(gcnt, 1u, __ATOMIC_RELEASE, AGENT_SCOPE);
      int it = 0;
      while (__hip_atomic_load(gcnt, __ATOMIC_RELAXED, AGENT_SCOPE) < target && ++it < SPIN_CAP) {}
      (void)__hip_atomic_load(gcnt, __ATOMIC_ACQUIRE, AGENT_SCOPE);
    }
    __syncthreads();
  };

  // lane's weight row: n = (wid&1)*16 + m; gate = n>>3, unit = n&7
  const int nl = (wid & 1) * 16 + m;
  const int gw = ((nl >> 3) << 9) + rowg * 8 + (nl & 7);

  short8 wb[28];

  // ================= encoder weights -> VGPRs =================
  // wid<2: wb[0..3]=eWih0 t0-3 | wb[4..19]=eWhh0 t0-15 | wb[20..25]=eWih1 t0-5
  // wid>=2: wb[0..9]=eWih1 t6-15 | wb[10..25]=eWhh1 t0-15
  if (wid < 2) {
    #pragma unroll
    for (int t = 0; t < 4; ++t)  wb[t]      = ldw(eWih0, 128, gw, t * 32);
    #pragma unroll
    for (int t = 0; t < 16; ++t) wb[4 + t]  = ldw(eWhh0, 512, gw, t * 32);
    #pragma unroll
    for (int t = 0; t < 6; ++t)  wb[20 + t] = ldw(eWih1, 512, gw, t * 32);
  } else {
    #pragma unroll
    for (int t = 0; t < 10; ++t) wb[t]      = ldw(eWih1, 512, gw, (6 + t) * 32);
    #pragma unroll
    for (int t = 0; t < 16; ++t) wb[10 + t] = ldw(eWhh1, 512, gw, t * 32);
  }
  if (tid < 64) {
    int li = tid >> 5, n = tid & 31;
    int g = ((n >> 3) << 9) + rowg * 8 + (n & 7);
    sBias[li * 32 + n] = li ? (ebi1[g] + ebh1[g]) : (ebi0[g] + ebh0[g]);
  }
  sC[tid] = 0.f;
  stage_xt(0);
  __syncthreads();

  // ================= encoder scan =====
  for (int s = 0; s <= 1024; ++s) {
    const bool L0 = (s < 1024), L1 = (s >= 1);
    flag_wait((u32)s);
    stage_slot((s + 2) % 3, (s + 1) % 3, true, s >= 1);   // h0[s-1], h1[s-2]
    __syncthreads();
    clears(s);

    f32x4 accA = {0.f,0.f,0.f,0.f}, accB = {0.f,0.f,0.f,0.f};
    if (wid < 2) {
      if (L0) {
        #pragma unroll
        for (int t = 0; t < 4; ++t) {
          short8 a = *(const short8*)(sX + m * 136 + t * 32 + qo);
          accA = __builtin_amdgcn_mfma_f32_16x16x32_bf16(a, wb[t], accA, 0, 0, 0);
        }
      }
      #pragma unroll
      for (int t = 0; t < 16; ++t) {
        short8 a = *(const short8*)(sH0 + m * 520 + t * 32 + qo);
        if (L0) accA = __builtin_amdgcn_mfma_f32_16x16x32_bf16(a, wb[4 + t], accA, 0, 0, 0);
        if (L1 && t < 6) accB = __builtin_amdgcn_mfma_f32_16x16x32_bf16(a, wb[20 + t], accB, 0, 0, 0);
      }
    } else if (L1) {
      #pragma unroll
      for (int t = 0; t < 10; ++t) {
        short8 a = *(const short8*)(sH0 + m * 520 + (6 + t) * 32 + qo);
        accA = __builtin_amdgcn_mfma_f32_16x16x32_bf16(a, wb[t], accA, 0, 0, 0);
      }
      #pragma unroll
      for (int t = 0; t < 16; ++t) {
        short8 a = *(const short8*)(sH1 + m * 520 + t * 32 + qo);
        accA = __builtin_amdgcn_mfma_f32_16x16x32_bf16(a, wb[10 + t], accA, 0, 0, 0);
      }
    }
    if (wid < 2) { if (L0) spstore(wid, accA); if (L1) spstore(4 + wid, accB); }
    else         { if (L1) spstore(wid, accA); }
    __syncthreads();
    act_store(L0, L1, s % 3, (s + 2) % 3);     // h0[s]->q s%3, h1[s-1]->q (s-1)%3
    if (s + 1 < 1024) stage_xt(s + 1);         // x prefetch, off critical path
    if (tid == 0)
      __hip_atomic_store(myflag, (u32)(s + 1), __ATOMIC_RELAXED, AGENT_SCOPE);
  }

  // ================= latent: z = h1[1023] @ tlW^T + tlb ====================
  flag_wait(1025u);
  {  // h1[1023] in q0
    const u32* b1 = h1r + ((0 * 4 + col) << 12) + tid;
    u32 v1[16];
    int it = 0; bool ok = false;
    while (!ok && it++ < POLL_CAP) {
      ok = true;
      #pragma unroll
      for (int i = 0; i < 16; ++i) {
        v1[i] = __hip_atomic_load(b1 + i * 256, __ATOMIC_RELAXED, AGENT_SCOPE);
        ok &= (v1[i] != SENT);
      }
    }
    u32* dH1 = (u32*)sH1;
    #pragma unroll
    for (int i = 0; i < 16; ++i) {
      int g = i * 256 + tid;
      dH1[((g >> 2) & 15) * 260 + (g >> 6) * 4 + (g & 3)] = v1[i];
    }
  }
  __syncthreads();
  if (tid < 16) {
    int b = tid;
    float acc = tlb[rowg];
    for (int kk = 0; kk < 512; kk += 8) {
      short8 hv = *(const short8*)(sH1 + b * 520 + kk);
      #pragma unroll
      for (int j = 0; j < 8; ++j) acc += bf2f((u16)hv[j]) * tlW[rowg * 512 + kk + j];
    }
    int gb = col * 16 + b;
    __hip_atomic_store((u32*)zbuf + gb * 64 + rowg, __float_as_uint(acc),
                       __ATOMIC_RELAXED, AGENT_SCOPE);
    out[8388608 + gb * 64 + rowg] = acc;
  }
  gbar(256);

  // ---- reset rings for decoder ----
  if (tid < 64) {
    #pragma unroll
    for (int q = 0; q < 3; ++q) {
      __hip_atomic_store(h0r + ((q * 4 + col) << 12) + (rowg << 6) + tid,
                         SENT, __ATOMIC_RELAXED, AGENT_SCOPE);
      __hip_atomic_store(h1r + ((q * 4 + col) << 12) + (rowg << 6) + tid,
                         SENT, __ATOMIC_RELAXED, AGENT_SCOPE);
    }
  }

  // ================= decoder weights -> VGPRs ==============================
  // wid<2: wb[0..15]=dWhh0 | wb[16..19]=dWih1 t0-3 | wb[20..27]=opW k-tiles
  // wid>=2: wb[0..11]=dWih1 t4-15 | wb[12..27]=dWhh1 t0-15
  if (wid < 2) {
    #pragma unroll
    for (int t = 0; t < 16; ++t) wb[t]      = ldw(dWhh0, 512, gw, t * 32);
    #pragma unroll
    for (int t = 0; t < 4; ++t)  wb[16 + t] = ldw(dWih1, 512, gw, t * 32);
    int rrow = rowg * 2 + (m < 2 ? m : 0);
    #pragma unroll
    for (int t = 0; t < 8; ++t)  wb[20 + t] = ldw(opW, 512, rrow, ((wid & 1) * 8 + t) * 32);
  } else {
    #pragma unroll
    for (int t = 0; t < 12; ++t) wb[t]      = ldw(dWih1, 512, gw, (4 + t) * 32);
    #pragma unroll
    for (int t = 0; t < 16; ++t) wb[12 + t] = ldw(dWhh1, 512, gw, t * 32);
  }
  if (tid < 64) {
    int li = tid >> 5, n = tid & 31;
    int g = ((n >> 3) << 9) + rowg * 8 + (n & 7);
    sBias[li * 32 + n] = li ? (dbi1[g] + dbh1[g]) : (dbi0[g] + dbh0[g]);
  }
  if (tid < 2) sOPB[tid] = opb[rowg * 2 + tid];
  sC[tid] = 0.f;

  // init_h = tanh(z @ lhW^T + lhb), torch flat view (L,B,H) -> q2 as h[-1]
  {
    int ri = tid >> 4, kk = (tid & 15) * 4;
    int zr = ((ri >> 3) << 5) + 8 * col + (ri & 7);
    #pragma unroll
    for (int j = 0; j < 4; ++j)
      sZ[ri * 64 + kk + j] = __uint_as_float(
          __hip_atomic_load((u32*)zbuf + zr * 64 + kk + j, __ATOMIC_RELAXED, AGENT_SCOPE));
  }
  __syncthreads();   // also drains the SENT resets (all waves)
  {
    int li = tid >> 7, hh = (tid >> 4) & 7, qb = (tid >> 3) & 1, u = tid & 7;
    int cc = qb * 512 + rowg * 8 + u;
    int bl = 2 * hh + qb;
    float acc2 = lhb[cc];
    const float* lw = lhW + (size_t)cc * 64;
    #pragma unroll 8
    for (int k = 0; k < 64; ++k) acc2 += sZ[(li * 8 + hh) * 64 + k] * lw[k];
    u16 hb = f2bf(tanha(acc2));
    u32 other = __shfl_xor((u32)hb, 1);
    if (!(u & 1)) {
      u32 v = (u32)hb | (other << 16);
      u32* ring = li ? h1r : h0r;
      __hip_atomic_store(ring + ((2 * 4 + col) << 12) + (rowg << 6) + bl * 4 + (u >> 1),
                         v, __ATOMIC_RELAXED, AGENT_SCOPE);
    }
  }
  gbar(512);

  // ================= decoder scan + fused MFMA recon =======================
  for (int s = 0; s <= 1025; ++s) {
    const bool L0 = (s < 1024), L1 = (s >= 1 && s <= 1024), RC = (s >= 2);
    flag_wait((u32)(1025 + s));
    stage_slot((s + 2) % 3, (s + 1) % 3, s <= 1024, s >= 1);
    __syncthreads();
    clears(s);

    f32x4 accA = {0.f,0.f,0.f,0.f}, accB = {0.f,0.f,0.f,0.f}, accR = {0.f,0.f,0.f,0.f};
    if (wid < 2) {
      if (L0 || L1) {
        #pragma unroll
        for (int t = 0; t < 16; ++t) {
          short8 a = *(const short8*)(sH0 + m * 520 + t * 32 + qo);
          if (L0) accA = __builtin_amdgcn_mfma_f32_16x16x32_bf16(a, wb[t], accA, 0, 0, 0);
          if (L1 && t < 4) accB = __builtin_amdgcn_mfma_f32_16x16x32_bf16(a, wb[16 + t], accB, 0, 0, 0);
        }
      }
      if (RC) {
        #pragma unroll
        for (int t = 0; t < 8; ++t) {
          short8 a = *(const short8*)(sH1 + m * 520 + ((wid & 1) * 8 + t) * 32 + qo);
          accR = __builtin_amdgcn_mfma_f32_16x16x32_bf16(a, wb[20 + t], accR, 0, 0, 0);
        }
      }
    } else if (L1) {
      #pragma unroll
      for (int t = 0; t < 12; ++t) {
        short8 a = *(const short8*)(sH0 + m * 520 + (4 + t) * 32 + qo);
        accA = __builtin_amdgcn_mfma_f32_16x16x32_bf16(a, wb[t], accA, 0, 0, 0);
      }
      #pragma unroll
      for (int t = 0; t < 16; ++t) {
        short8 a = *(const short8*)(sH1 + m * 520 + t * 32 + qo);
        accA = __builtin_amdgcn_mfma_f32_16x16x32_bf16(a, wb[12 + t], accA, 0, 0, 0);
      }
    }
    if (wid < 2) {
      if (L0) spstore(wid, accA);
      if (L1) spstore(4 + wid, accB);
      if (RC) spstore(6 + wid, accR);
    } else if (L1) spstore(wid, accA);
    __syncthreads();
    act_store(L0, L1, s % 3, (s + 2) % 3);
    if (RC && tid < 32) {   // finish recon[t=s-2]: d = rowg*2 + (tid&1)
      int b2 = tid >> 1, d2 = tid & 1;
      float sum = sOPB[d2] + sP[6*256 + b2*16 + d2] + sP[7*256 + b2*16 + d2];
      out[(size_t)(col * 16 + b2) * 131072 + (size_t)(s - 2) * 128 + rowg * 2 + d2]
          = sigm(sum);
    }
    if (tid == 0)
      __hip_atomic_store(myflag, (u32)(1026 + s), __ATOMIC_RELAXED, AGENT_SCOPE);
  }
}

extern "C" void kernel_launch(void* const* d_in, const int* in_sizes, int n_in,
                              void* d_out, int out_size, void* d_ws, size_t ws_size,
                              hipStream_t stream) {
  (void)in_sizes; (void)n_in; (void)out_size; (void)ws_size;
  char* ws = (char*)d_ws;
  hipMemsetAsync(ws, 0, 32768, stream);                 // gcnt, zbuf, flags
  hipMemsetAsync(ws + 32768, 0xFF, 131072, stream);     // h0 q0,q1 = SENT
  hipMemsetAsync(ws + 163840, 0x00, 65536, stream);     // h0 q2 = 0 (h0[-1])
  hipMemsetAsync(ws + 229376, 0xFF, 131072, stream);    // h1 q0,q1 = SENT
  hipMemsetAsync(ws + 360448, 0x00, 65536, stream);     // h1 q2 = 0 (h1[-1])
  lstm_ae_kernel<<<dim3(256), dim3(256), 0, stream>>>(
      (const float*)d_in[0],
      (const float*)d_in[1],  (const float*)d_in[2],
      (const float*)d_in[3],  (const float*)d_in[4],
      (const float*)d_in[5],  (const float*)d_in[6],
      (const float*)d_in[7],  (const float*)d_in[8],
      (const float*)d_in[10],
      (const float*)d_in[11], (const float*)d_in[12],
      (const float*)d_in[13], (const float*)d_in[14],
      (const float*)d_in[15], (const float*)d_in[16],
      (const float*)d_in[17], (const float*)d_in[18],
      (const float*)d_in[19], (const float*)d_in[20],
      (const float*)d_in[21], (const float*)d_in[22],
      (float*)d_out, (char*)d_ws);
}

// Round 6
// 6804.996 us; speedup vs baseline: 2.6032x; 2.6032x over previous
//
#include <hip/hip_runtime.h>
#include <cstdint>
#include <cstddef>

typedef unsigned short u16;
typedef unsigned int u32;
typedef __attribute__((ext_vector_type(8))) short short8;
typedef __attribute__((ext_vector_type(4))) float f32x4;

#define AGENT_SCOPE __HIP_MEMORY_SCOPE_AGENT
#define SPIN_CAP 20000000
#define POLL_CAP 200000
#define SENT 0xFFFFFFFFu

__device__ __forceinline__ u16 f2bf(float f) {
  u32 u = __float_as_uint(f);
  return (u16)((u + 0x7FFFu + ((u >> 16) & 1u)) >> 16);
}
__device__ __forceinline__ float bf2f(u16 s) { return __uint_as_float(((u32)s) << 16); }
__device__ __forceinline__ float sigm(float x) { return 1.f / (1.f + __expf(-x)); }
__device__ __forceinline__ float tanha(float x) { return 1.f - 2.f / (__expf(2.f * x) + 1.f); }
__device__ __forceinline__ void wait_vm0() { asm volatile("s_waitcnt vmcnt(0)" ::: "memory"); }

// Barrier-free persistent LSTM autoencoder (R4 sync + R5 compute balance +
// split accumulator chains).
// col = bid&3 (16 batches), rowg = bid>>2 in [0,64) (8 hidden units).
// Sync: consumers poll the DATA lines of the depth-3 LLC ring until no dword
// is SENT — the poll RETURNS the data (one LLC hop, spread over 512 lines).
// R5 lesson: dedicated flag lines spin-polled by 1024 waves starve the
// producers' flag writes at the LLC (3x regression) — never concentrate
// spin-waits on few lines.
__global__ void __launch_bounds__(256, 1)
lstm_ae_kernel(const float* __restrict__ x,
    const float* __restrict__ eWih0, const float* __restrict__ eWhh0,
    const float* __restrict__ ebi0,  const float* __restrict__ ebh0,
    const float* __restrict__ eWih1, const float* __restrict__ eWhh1,
    const float* __restrict__ ebi1,  const float* __restrict__ ebh1,
    const float* __restrict__ dWhh0,
    const float* __restrict__ dbi0,  const float* __restrict__ dbh0,
    const float* __restrict__ dWih1, const float* __restrict__ dWhh1,
    const float* __restrict__ dbi1,  const float* __restrict__ dbh1,
    const float* __restrict__ tlW,   const float* __restrict__ tlb,
    const float* __restrict__ lhW,   const float* __restrict__ lhb,
    const float* __restrict__ opW,   const float* __restrict__ opb,
    float* __restrict__ out, char* __restrict__ wsb)
{
  __shared__ __align__(16) u16 sH0[16 * 520];
  __shared__ __align__(16) u16 sH1[16 * 520];
  __shared__ __align__(16) u16 sX[16 * 136];
  __shared__ float sP[8 * 256];   // 0,1: L0 | 2,3: L1 main | 4,5: L1 partial | 6,7: recon
  __shared__ float sBias[64];
  __shared__ float sC[256];
  __shared__ float sZ[16 * 64];
  __shared__ float sOPB[2];

  u32* gcnt  = (u32*)wsb;
  float* zbuf= (float*)(wsb + 4096);
  u32* h0r   = (u32*)(wsb + 32768);              // [3 q][4 col][64 rowg][64 dw]
  u32* h1r   = (u32*)(wsb + 229376);

  const int tid  = threadIdx.x;
  const int col  = blockIdx.x & 3;
  const int rowg = blockIdx.x >> 2;
  const int wid  = tid >> 6;
  const int lane = tid & 63;
  const int m    = lane & 15;
  const int qo   = (lane >> 4) * 8;

  // fused poll+fetch: SENT-verified data read + LDS scatter (R4-verified)
  auto stage_slot = [&](int q0, int q1, bool p0on, bool p1on) {
    const u32* b0 = h0r + ((q0 * 4 + col) << 12) + tid;
    const u32* b1 = h1r + ((q1 * 4 + col) << 12) + tid;
    u32 v0[16], v1[16];
    int it = 0; bool ok = false;
    while (!ok && it++ < POLL_CAP) {
      ok = true;
      if (p0on) {
        #pragma unroll
        for (int i = 0; i < 16; ++i) {
          v0[i] = __hip_atomic_load(b0 + i * 256, __ATOMIC_RELAXED, AGENT_SCOPE);
          ok &= (v0[i] != SENT);
        }
      }
      if (p1on) {
        #pragma unroll
        for (int i = 0; i < 16; ++i) {
          v1[i] = __hip_atomic_load(b1 + i * 256, __ATOMIC_RELAXED, AGENT_SCOPE);
          ok &= (v1[i] != SENT);
        }
      }
    }
    u32* dH0 = (u32*)sH0; u32* dH1 = (u32*)sH1;
    #pragma unroll
    for (int i = 0; i < 16; ++i) {
      int g = i * 256 + tid;
      int rg = g >> 6, b = (g >> 2) & 15, udw = g & 3;
      if (p0on) dH0[b * 260 + rg * 4 + udw] = v0[i];
      if (p1on) dH1[b * 260 + rg * 4 + udw] = v1[i];
    }
  };

  auto clears = [&](int s) {
    if (tid < 64) {
      int cq0 = (s + 1) % 3, cq1 = s % 3;
      __hip_atomic_store(h0r + ((cq0 * 4 + col) << 12) + (rowg << 6) + tid,
                         SENT, __ATOMIC_RELAXED, AGENT_SCOPE);
      __hip_atomic_store(h1r + ((cq1 * 4 + col) << 12) + (rowg << 6) + tid,
                         SENT, __ATOMIC_RELAXED, AGENT_SCOPE);
    }
  };

  auto stage_xt = [&](int s) {
    int b = tid >> 4, seg = tid & 15;
    const float* p = x + (size_t)(col * 16 + b) * 131072 + (size_t)s * 128 + seg * 8;
    float4 f0 = *(const float4*)p, f1 = *(const float4*)(p + 4);
    uint4 v;
    v.x = (u32)f2bf(f0.x) | ((u32)f2bf(f0.y) << 16);
    v.y = (u32)f2bf(f0.z) | ((u32)f2bf(f0.w) << 16);
    v.z = (u32)f2bf(f1.x) | ((u32)f2bf(f1.y) << 16);
    v.w = (u32)f2bf(f1.z) | ((u32)f2bf(f1.w) << 16);
    *(uint4*)(sX + b * 136 + seg * 8) = v;
  };

  auto ldw = [&](const float* W, int ld, int row, int kofs) -> short8 {
    const float* p = W + (size_t)row * ld + kofs + qo;
    float4 f0 = *(const float4*)p, f1 = *(const float4*)(p + 4);
    short8 r;
    r[0] = (short)f2bf(f0.x); r[1] = (short)f2bf(f0.y);
    r[2] = (short)f2bf(f0.z); r[3] = (short)f2bf(f0.w);
    r[4] = (short)f2bf(f1.x); r[5] = (short)f2bf(f1.y);
    r[6] = (short)f2bf(f1.z); r[7] = (short)f2bf(f1.w);
    return r;
  };

  auto spstore = [&](int slot, const f32x4& a) {
    int mb = (lane >> 4) * 4;
    #pragma unroll
    for (int r = 0; r < 4; ++r) sP[slot * 256 + (mb + r) * 16 + m] = a[r];
  };

  // gates: L0 = slots 0,1 (full); L1 = slots 2,3 (main) + 4,5 (partials)
  auto act_store = [&](bool L0a, bool L1a, int q0, int q1) {
    int li = tid >> 7, b = (tid >> 3) & 15, u = tid & 7;
    bool actv = li ? L1a : L0a;
    float hv = 0.f;
    if (actv) {
      float gi, gf, gg, go;
      if (li == 0) {
        gi = sP[0*256 + b*16 + u];       gf = sP[0*256 + b*16 + 8 + u];
        gg = sP[1*256 + b*16 + u];       go = sP[1*256 + b*16 + 8 + u];
      } else {
        gi = sP[2*256 + b*16 + u]     + sP[4*256 + b*16 + u];
        gf = sP[2*256 + b*16 + 8 + u] + sP[4*256 + b*16 + 8 + u];
        gg = sP[3*256 + b*16 + u]     + sP[5*256 + b*16 + u];
        go = sP[3*256 + b*16 + 8 + u] + sP[5*256 + b*16 + 8 + u];
      }
      gi += sBias[li*32 + u];      gf += sBias[li*32 + 8 + u];
      gg += sBias[li*32 + 16 + u]; go += sBias[li*32 + 24 + u];
      float c = sC[(li*16 + b)*8 + u];
      c = sigm(gf)*c + sigm(gi)*tanha(gg);
      sC[(li*16 + b)*8 + u] = c;
      hv = sigm(go)*tanha(c);
    }
    u16 hb = f2bf(hv);
    u32 other = __shfl_xor((u32)hb, 1);
    if (actv && !(u & 1)) {
      u32 v = (u32)hb | (other << 16);
      u32* ring = li ? h1r : h0r;
      int q = li ? q1 : q0;
      __hip_atomic_store(ring + ((q * 4 + col) << 12) + (rowg << 6) + b * 4 + (u >> 1),
                         v, __ATOMIC_RELAXED, AGENT_SCOPE);
    }
  };

  auto gbar = [&](u32 target) {
    __syncthreads();
    if (tid == 0) {
      __hip_atomic_fetch_add(gcnt, 1u, __ATOMIC_RELEASE, AGENT_SCOPE);
      int it = 0;
      while (__hip_atomic_load(gcnt, __ATOMIC_RELAXED, AGENT_SCOPE) < target && ++it < SPIN_CAP) {}
      (void)__hip_atomic_load(gcnt, __ATOMIC_ACQUIRE, AGENT_SCOPE);
    }
    __syncthreads();
  };

  // lane's weight row: n = (wid&1)*16 + m; gate = n>>3, unit = n&7
  const int nl = (wid & 1) * 16 + m;
  const int gw = ((nl >> 3) << 9) + rowg * 8 + (nl & 7);

  short8 wb[28];

  // ================= encoder weights -> VGPRs =================
  // wid<2: wb[0..3]=eWih0 | wb[4..19]=eWhh0 | wb[20..25]=eWih1 t0-5
  // wid>=2: wb[0..9]=eWih1 t6-15 | wb[10..25]=eWhh1
  if (wid < 2) {
    #pragma unroll
    for (int t = 0; t < 4; ++t)  wb[t]      = ldw(eWih0, 128, gw, t * 32);
    #pragma unroll
    for (int t = 0; t < 16; ++t) wb[4 + t]  = ldw(eWhh0, 512, gw, t * 32);
    #pragma unroll
    for (int t = 0; t < 6; ++t)  wb[20 + t] = ldw(eWih1, 512, gw, t * 32);
  } else {
    #pragma unroll
    for (int t = 0; t < 10; ++t) wb[t]      = ldw(eWih1, 512, gw, (6 + t) * 32);
    #pragma unroll
    for (int t = 0; t < 16; ++t) wb[10 + t] = ldw(eWhh1, 512, gw, t * 32);
  }
  if (tid < 64) {
    int li = tid >> 5, n = tid & 31;
    int g = ((n >> 3) << 9) + rowg * 8 + (n & 7);
    sBias[li * 32 + n] = li ? (ebi1[g] + ebh1[g]) : (ebi0[g] + ebh0[g]);
  }
  sC[tid] = 0.f;
  stage_xt(0);
  __syncthreads();

  // ================= encoder scan =====
  for (int s = 0; s <= 1024; ++s) {
    const bool L0 = (s < 1024), L1 = (s >= 1);
    stage_slot((s + 2) % 3, (s + 1) % 3, true, s >= 1);   // h0[s-1], h1[s-2]
    __syncthreads();
    clears(s);

    f32x4 a1 = {0.f,0.f,0.f,0.f}, a2 = {0.f,0.f,0.f,0.f}, a3 = {0.f,0.f,0.f,0.f};
    if (wid < 2) {
      if (L0) {
        #pragma unroll
        for (int t = 0; t < 4; ++t) {
          short8 a = *(const short8*)(sX + m * 136 + t * 32 + qo);
          a1 = __builtin_amdgcn_mfma_f32_16x16x32_bf16(a, wb[t], a1, 0, 0, 0);
        }
      }
      #pragma unroll
      for (int t = 0; t < 16; ++t) {
        short8 a = *(const short8*)(sH0 + m * 520 + t * 32 + qo);
        if (L0) {
          if (t < 8) a1 = __builtin_amdgcn_mfma_f32_16x16x32_bf16(a, wb[4 + t], a1, 0, 0, 0);
          else       a2 = __builtin_amdgcn_mfma_f32_16x16x32_bf16(a, wb[4 + t], a2, 0, 0, 0);
        }
        if (L1 && t < 6) a3 = __builtin_amdgcn_mfma_f32_16x16x32_bf16(a, wb[20 + t], a3, 0, 0, 0);
      }
      if (L0) spstore(wid, a1 + a2);
      if (L1) spstore(4 + wid, a3);
    } else if (L1) {
      #pragma unroll
      for (int t = 0; t < 10; ++t) {
        short8 a = *(const short8*)(sH0 + m * 520 + (6 + t) * 32 + qo);
        a1 = __builtin_amdgcn_mfma_f32_16x16x32_bf16(a, wb[t], a1, 0, 0, 0);
      }
      #pragma unroll
      for (int t = 0; t < 16; ++t) {
        short8 a = *(const short8*)(sH1 + m * 520 + t * 32 + qo);
        if (t < 8) a2 = __builtin_amdgcn_mfma_f32_16x16x32_bf16(a, wb[10 + t], a2, 0, 0, 0);
        else       a3 = __builtin_amdgcn_mfma_f32_16x16x32_bf16(a, wb[10 + t], a3, 0, 0, 0);
      }
      spstore(wid, a1 + a2 + a3);
    }
    __syncthreads();
    act_store(L0, L1, s % 3, (s + 2) % 3);     // h0[s]->q s%3, h1[s-1]->q (s-1)%3
    if (s + 1 < 1024) stage_xt(s + 1);         // x prefetch, off critical path
  }

  // ================= latent: z = h1[1023] @ tlW^T + tlb ====================
  {  // h1[1023] in q0
    const u32* b1 = h1r + ((0 * 4 + col) << 12) + tid;
    u32 v1[16];
    int it = 0; bool ok = false;
    while (!ok && it++ < POLL_CAP) {
      ok = true;
      #pragma unroll
      for (int i = 0; i < 16; ++i) {
        v1[i] = __hip_atomic_load(b1 + i * 256, __ATOMIC_RELAXED, AGENT_SCOPE);
        ok &= (v1[i] != SENT);
      }
    }
    u32* dH1 = (u32*)sH1;
    #pragma unroll
    for (int i = 0; i < 16; ++i) {
      int g = i * 256 + tid;
      dH1[((g >> 2) & 15) * 260 + (g >> 6) * 4 + (g & 3)] = v1[i];
    }
  }
  __syncthreads();
  if (tid < 16) {
    int b = tid;
    float acc = tlb[rowg];
    for (int kk = 0; kk < 512; kk += 8) {
      short8 hv = *(const short8*)(sH1 + b * 520 + kk);
      #pragma unroll
      for (int j = 0; j < 8; ++j) acc += bf2f((u16)hv[j]) * tlW[rowg * 512 + kk + j];
    }
    int gb = col * 16 + b;
    __hip_atomic_store((u32*)zbuf + gb * 64 + rowg, __float_as_uint(acc),
                       __ATOMIC_RELAXED, AGENT_SCOPE);
    out[8388608 + gb * 64 + rowg] = acc;
  }
  gbar(256);

  // ---- reset rings for decoder ----
  if (tid < 64) {
    #pragma unroll
    for (int q = 0; q < 3; ++q) {
      __hip_atomic_store(h0r + ((q * 4 + col) << 12) + (rowg << 6) + tid,
                         SENT, __ATOMIC_RELAXED, AGENT_SCOPE);
      __hip_atomic_store(h1r + ((q * 4 + col) << 12) + (rowg << 6) + tid,
                         SENT, __ATOMIC_RELAXED, AGENT_SCOPE);
    }
  }

  // ================= decoder weights -> VGPRs ==============================
  // wid<2: wb[0..15]=dWhh0 | wb[16..19]=dWih1 t0-3 | wb[20..27]=opW k-tiles
  // wid>=2: wb[0..11]=dWih1 t4-15 | wb[12..27]=dWhh1
  if (wid < 2) {
    #pragma unroll
    for (int t = 0; t < 16; ++t) wb[t]      = ldw(dWhh0, 512, gw, t * 32);
    #pragma unroll
    for (int t = 0; t < 4; ++t)  wb[16 + t] = ldw(dWih1, 512, gw, t * 32);
    int rrow = rowg * 2 + (m < 2 ? m : 0);
    #pragma unroll
    for (int t = 0; t < 8; ++t)  wb[20 + t] = ldw(opW, 512, rrow, ((wid & 1) * 8 + t) * 32);
  } else {
    #pragma unroll
    for (int t = 0; t < 12; ++t) wb[t]      = ldw(dWih1, 512, gw, (4 + t) * 32);
    #pragma unroll
    for (int t = 0; t < 16; ++t) wb[12 + t] = ldw(dWhh1, 512, gw, t * 32);
  }
  if (tid < 64) {
    int li = tid >> 5, n = tid & 31;
    int g = ((n >> 3) << 9) + rowg * 8 + (n & 7);
    sBias[li * 32 + n] = li ? (dbi1[g] + dbh1[g]) : (dbi0[g] + dbh0[g]);
  }
  if (tid < 2) sOPB[tid] = opb[rowg * 2 + tid];
  sC[tid] = 0.f;

  // init_h = tanh(z @ lhW^T + lhb), torch flat view (L,B,H) -> q2 as h[-1]
  {
    int ri = tid >> 4, kk = (tid & 15) * 4;
    int zr = ((ri >> 3) << 5) + 8 * col + (ri & 7);
    #pragma unroll
    for (int j = 0; j < 4; ++j)
      sZ[ri * 64 + kk + j] = __uint_as_float(
          __hip_atomic_load((u32*)zbuf + zr * 64 + kk + j, __ATOMIC_RELAXED, AGENT_SCOPE));
  }
  __syncthreads();   // drains the SENT resets before init_h data stores
  {
    int li = tid >> 7, hh = (tid >> 4) & 7, qb = (tid >> 3) & 1, u = tid & 7;
    int cc = qb * 512 + rowg * 8 + u;
    int bl = 2 * hh + qb;
    float acc2 = lhb[cc];
    const float* lw = lhW + (size_t)cc * 64;
    #pragma unroll 8
    for (int k = 0; k < 64; ++k) acc2 += sZ[(li * 8 + hh) * 64 + k] * lw[k];
    u16 hb = f2bf(tanha(acc2));
    u32 other = __shfl_xor((u32)hb, 1);
    if (!(u & 1)) {
      u32 v = (u32)hb | (other << 16);
      u32* ring = li ? h1r : h0r;
      __hip_atomic_store(ring + ((2 * 4 + col) << 12) + (rowg << 6) + bl * 4 + (u >> 1),
                         v, __ATOMIC_RELAXED, AGENT_SCOPE);
    }
  }
  gbar(512);

  // ================= decoder scan + fused MFMA recon =======================
  for (int s = 0; s <= 1025; ++s) {
    const bool L0 = (s < 1024), L1 = (s >= 1 && s <= 1024), RC = (s >= 2);
    stage_slot((s + 2) % 3, (s + 1) % 3, s <= 1024, s >= 1);
    __syncthreads();
    clears(s);

    f32x4 a1 = {0.f,0.f,0.f,0.f}, a2 = {0.f,0.f,0.f,0.f}, a3 = {0.f,0.f,0.f,0.f};
    f32x4 accR = {0.f,0.f,0.f,0.f};
    if (wid < 2) {
      if (L0 || L1) {
        #pragma unroll
        for (int t = 0; t < 16; ++t) {
          short8 a = *(const short8*)(sH0 + m * 520 + t * 32 + qo);
          if (L0) {
            if (t < 8) a1 = __builtin_amdgcn_mfma_f32_16x16x32_bf16(a, wb[t], a1, 0, 0, 0);
            else       a2 = __builtin_amdgcn_mfma_f32_16x16x32_bf16(a, wb[t], a2, 0, 0, 0);
          }
          if (L1 && t < 4) a3 = __builtin_amdgcn_mfma_f32_16x16x32_bf16(a, wb[16 + t], a3, 0, 0, 0);
        }
      }
      if (RC) {
        #pragma unroll
        for (int t = 0; t < 8; ++t) {
          short8 a = *(const short8*)(sH1 + m * 520 + ((wid & 1) * 8 + t) * 32 + qo);
          accR = __builtin_amdgcn_mfma_f32_16x16x32_bf16(a, wb[20 + t], accR, 0, 0, 0);
        }
      }
      if (L0) spstore(wid, a1 + a2);
      if (L1) spstore(4 + wid, a3);
      if (RC) spstore(6 + wid, accR);
    } else if (L1) {
      #pragma unroll
      for (int t = 0; t < 12; ++t) {
        short8 a = *(const short8*)(sH0 + m * 520 + (4 + t) * 32 + qo);
        a1 = __builtin_amdgcn_mfma_f32_16x16x32_bf16(a, wb[t], a1, 0, 0, 0);
      }
      #pragma unroll
      for (int t = 0; t < 16; ++t) {
        short8 a = *(const short8*)(sH1 + m * 520 + t * 32 + qo);
        if (t < 8) a2 = __builtin_amdgcn_mfma_f32_16x16x32_bf16(a, wb[12 + t], a2, 0, 0, 0);
        else       a3 = __builtin_amdgcn_mfma_f32_16x16x32_bf16(a, wb[12 + t], a3, 0, 0, 0);
      }
      spstore(wid, a1 + a2 + a3);
    }
    __syncthreads();
    act_store(L0, L1, s % 3, (s + 2) % 3);
    if (RC && tid < 32) {   // finish recon[t=s-2]: d = rowg*2 + (tid&1)
      int b2 = tid >> 1, d2 = tid & 1;
      float sum = sOPB[d2] + sP[6*256 + b2*16 + d2] + sP[7*256 + b2*16 + d2];
      out[(size_t)(col * 16 + b2) * 131072 + (size_t)(s - 2) * 128 + rowg * 2 + d2]
          = sigm(sum);
    }
  }
}

extern "C" void kernel_launch(void* const* d_in, const int* in_sizes, int n_in,
                              void* d_out, int out_size, void* d_ws, size_t ws_size,
                              hipStream_t stream) {
  (void)in_sizes; (void)n_in; (void)out_size; (void)ws_size;
  char* ws = (char*)d_ws;
  hipMemsetAsync(ws, 0, 32768, stream);                 // gcnt, zbuf
  hipMemsetAsync(ws + 32768, 0xFF, 131072, stream);     // h0 q0,q1 = SENT
  hipMemsetAsync(ws + 163840, 0x00, 65536, stream);     // h0 q2 = 0 (h0[-1])
  hipMemsetAsync(ws + 229376, 0xFF, 131072, stream);    // h1 q0,q1 = SENT
  hipMemsetAsync(ws + 360448, 0x00, 65536, stream);     // h1 q2 = 0 (h1[-1])
  lstm_ae_kernel<<<dim3(256), dim3(256), 0, stream>>>(
      (const float*)d_in[0],
      (const float*)d_in[1],  (const float*)d_in[2],
      (const float*)d_in[3],  (const float*)d_in[4],
      (const float*)d_in[5],  (const float*)d_in[6],
      (const float*)d_in[7],  (const float*)d_in[8],
      (const float*)d_in[10],
      (const float*)d_in[11], (const float*)d_in[12],
      (const float*)d_in[13], (const float*)d_in[14],
      (const float*)d_in[15], (const float*)d_in[16],
      (const float*)d_in[17], (const float*)d_in[18],
      (const float*)d_in[19], (const float*)d_in[20],
      (const float*)d_in[21], (const float*)d_in[22],
      (float*)d_out, (char*)d_ws);
}